// Round 6
// baseline (1334.461 us; speedup 1.0000x reference)
//
#include <hip/hip_runtime.h>
#include <hip/hip_cooperative_groups.h>

namespace cg = cooperative_groups;

#define NB 32
#define NM 128
#define NL 32
#define NH 512
#define NV 32000
#define NHOPS 3
#define NEG_INF -1e9f

#define NBLK 512
#define NTHR 256
#define VC_D 32                 // v-rows per D chunk (2 MFMA v-tiles)
#define ND_CHUNK (NV / VC_D)    // 1000
#define VC_U 64                 // v-rows per U partial
#define NPART_U (NV / VC_U)     // 500
#define NQ 8                    // second-stage reduce fan-in

typedef __attribute__((ext_vector_type(8))) short bf16x8;
typedef __attribute__((ext_vector_type(4))) float f32x4;

__device__ __forceinline__ unsigned short f2bf(float x) {
    unsigned u = __float_as_uint(x);
    return (unsigned short)((u + 0x7fffu + ((u >> 16) & 1u)) >> 16);
}
__device__ __forceinline__ float bf2f(unsigned short h) {
    return __uint_as_float(((unsigned)h) << 16);
}

// ---------------------------------------------------------------------------
// One cooperative kernel for the whole 3-hop network.
// LDS: exactly 64 KiB, unioned between P1 (Ch/Cl bf16 tiles) and P2 (red).
// ---------------------------------------------------------------------------
__global__ __launch_bounds__(NTHR, 2)
void memnn_fused(const int* __restrict__ inputs, const int* __restrict__ lengths,
                 const float* __restrict__ enc, const float* __restrict__ C,
                 float* __restrict__ out,
                 float* __restrict__ D, float* __restrict__ w,
                 float* __restrict__ part, float* __restrict__ part2,
                 float* __restrict__ u1, float* __restrict__ u2,
                 unsigned short* __restrict__ uh, unsigned short* __restrict__ ul) {
    cg::grid_group grid = cg::this_grid();
    const int bid = blockIdx.x, tid = threadIdx.x;
    const int gtid = bid * NTHR + tid;

    __shared__ __align__(16) unsigned char smem[65536];      // 64 KiB exactly
    unsigned short* Ch = (unsigned short*)smem;              // [VC_D*NH] (P1)
    unsigned short* Cl = Ch + VC_D * NH;                     // [VC_D*NH] (P1)
    float* red = (float*)smem;                               // [2] (P2 only)

    // ---- P0: zero w; split enc -> uh/ul -------------------------------------
    {
        float4* w4 = reinterpret_cast<float4*>(w);
        for (int i = gtid; i < (NB * NV) / 4; i += NBLK * NTHR)
            w4[i] = make_float4(0.f, 0.f, 0.f, 0.f);
        if (gtid < NB * NH) {
            const float x = enc[gtid];
            const unsigned short hh = f2bf(x);
            uh[gtid] = hh;
            ul[gtid] = f2bf(x - bf2f(hh));
        }
    }
    grid.sync();

    for (int h = 0; h < NHOPS; ++h) {
        const float* Ct = C + (size_t)h * NV * NH;
        const float* Cn = C + (size_t)(h + 1) * NV * NH;
        const float* ucur = (h == 0) ? enc : (h == 1) ? u1 : u2;
        float* unext      = (h == 0) ? u1  : (h == 1) ? u2 : out;
        float* attn_out   = out + NB * NH + (size_t)h * NB * NM;

        // ---- P1: D[b][v] = u.C[v]  (split-bf16 MFMA, grid-strided chunks) ---
        for (int k = 0; k < 2; ++k) {
            const int chunk = bid + k * NBLK;
            if (chunk < ND_CHUNK) {
                const int vbase = chunk * VC_D;
                __syncthreads();                      // LDS reuse guard
#pragma unroll
                for (int s = 0; s < 16; ++s) {        // stage 32 rows, hi/lo
                    const int r = s * 2 + (tid >> 7);
                    const int c4 = tid & 127;
                    const float4 x = *reinterpret_cast<const float4*>(
                        Ct + ((size_t)(vbase + r) << 9) + (c4 << 2));
                    const unsigned short h0 = f2bf(x.x), h1 = f2bf(x.y),
                                         h2 = f2bf(x.z), h3 = f2bf(x.w);
                    const unsigned short l0 = f2bf(x.x - bf2f(h0)),
                                         l1 = f2bf(x.y - bf2f(h1)),
                                         l2 = f2bf(x.z - bf2f(h2)),
                                         l3 = f2bf(x.w - bf2f(h3));
                    const int us = ((r << 9) + (c4 << 2)) ^ ((r & 7) << 3);
                    *reinterpret_cast<ushort4*>(&Ch[us]) = make_ushort4(h0, h1, h2, h3);
                    *reinterpret_cast<ushort4*>(&Cl[us]) = make_ushort4(l0, l1, l2, l3);
                }
                __syncthreads();
                const int wv = tid >> 6, lane = tid & 63;
                const int mt = wv & 1, vt = wv >> 1;       // 2 m-tiles x 2 v-tiles
                const int arow = mt * 16 + (lane & 15);
                const int kblk = (lane >> 4) * 8;
                const int brow = vt * 16 + (lane & 15);
                f32x4 acc = {0.f, 0.f, 0.f, 0.f};
                for (int kt = 0; kt < 16; ++kt) {
                    const int koff = kt * 32 + kblk;
                    const bf16x8 ah = *reinterpret_cast<const bf16x8*>(uh + (arow << 9) + koff);
                    const bf16x8 al = *reinterpret_cast<const bf16x8*>(ul + (arow << 9) + koff);
                    const int rb = ((brow << 9) + koff) ^ ((brow & 7) << 3);
                    const bf16x8 bh = *reinterpret_cast<const bf16x8*>(&Ch[rb]);
                    const bf16x8 bl = *reinterpret_cast<const bf16x8*>(&Cl[rb]);
                    acc = __builtin_amdgcn_mfma_f32_16x16x32_bf16(ah, bh, acc, 0, 0, 0);
                    acc = __builtin_amdgcn_mfma_f32_16x16x32_bf16(ah, bl, acc, 0, 0, 0);
                    acc = __builtin_amdgcn_mfma_f32_16x16x32_bf16(al, bh, acc, 0, 0, 0);
                }
                const int vcol = vbase + vt * 16 + (lane & 15);
                const int b0 = mt * 16 + (lane >> 4) * 4;
#pragma unroll
                for (int r = 0; r < 4; ++r)
                    D[(size_t)(b0 + r) * NV + vcol] = acc[r];
            }
        }
        grid.sync();

        // ---- P2: scores -> softmax -> attn out -> w scatter (blocks 0..31) --
        if (bid < NB) {
            const int b = bid;
            int idx[NL];
            float s = NEG_INF;
            if (tid < NM) {
                const int4* ip = reinterpret_cast<const int4*>(
                    inputs + (((b << 7) + tid) << 5));
                const float* Db = D + (size_t)b * NV;
                float acc = 0.f;
#pragma unroll
                for (int q = 0; q < 8; ++q) {
                    const int4 i4 = ip[q];
                    idx[q * 4 + 0] = i4.x; idx[q * 4 + 1] = i4.y;
                    idx[q * 4 + 2] = i4.z; idx[q * 4 + 3] = i4.w;
                }
#pragma unroll
                for (int l = 0; l < NL; ++l) acc += Db[idx[l]];
                s = (lengths[(b << 7) + tid] == 0) ? NEG_INF : acc;
            }
            float mx = s;
#pragma unroll
            for (int o = 32; o; o >>= 1) mx = fmaxf(mx, __shfl_xor(mx, o, 64));
            if (tid < NM && (tid & 63) == 0) red[tid >> 6] = mx;
            __syncthreads();
            mx = fmaxf(red[0], red[1]);
            const float ee = (tid < NM) ? expf(s - mx) : 0.f;
            float sum = ee;
#pragma unroll
            for (int o = 32; o; o >>= 1) sum += __shfl_xor(sum, o, 64);
            __syncthreads();
            if (tid < NM && (tid & 63) == 0) red[tid >> 6] = sum;
            __syncthreads();
            if (tid < NM) {
                const float a = ee / (red[0] + red[1]);
                attn_out[(b << 7) + tid] = a;
                float* wb = w + (size_t)b * NV;
#pragma unroll
                for (int l = 0; l < NL; ++l) atomicAdd(&wb[idx[l]], a);
            }
        }
        grid.sync();

        // ---- P3: U partials over C[h+1] (blocks 0..499); then zero own w ----
        if (bid < NPART_U) {
            const int vbase = bid * VC_U;
            const int h0 = tid << 1;
            float2 acc[NB];
#pragma unroll
            for (int b = 0; b < NB; ++b) acc[b] = make_float2(0.f, 0.f);

            for (int v = 0; v < VC_U; v += 4) {
                const float2 c0 = *reinterpret_cast<const float2*>(Cn + ((size_t)(vbase + v + 0) << 9) + h0);
                const float2 c1 = *reinterpret_cast<const float2*>(Cn + ((size_t)(vbase + v + 1) << 9) + h0);
                const float2 c2 = *reinterpret_cast<const float2*>(Cn + ((size_t)(vbase + v + 2) << 9) + h0);
                const float2 c3 = *reinterpret_cast<const float2*>(Cn + ((size_t)(vbase + v + 3) << 9) + h0);
#pragma unroll
                for (int b = 0; b < NB; ++b) {
                    const float4 wv4 = *reinterpret_cast<const float4*>(
                        w + (size_t)b * NV + vbase + v);      // wave-uniform
                    acc[b].x += wv4.x * c0.x + wv4.y * c1.x + wv4.z * c2.x + wv4.w * c3.x;
                    acc[b].y += wv4.x * c0.y + wv4.y * c1.y + wv4.z * c2.y + wv4.w * c3.y;
                }
            }
            float* pb = part + (size_t)bid * (NB * NH);
#pragma unroll
            for (int b = 0; b < NB; ++b)
                *reinterpret_cast<float2*>(pb + (b << 9) + h0) = acc[b];
            __syncthreads();                       // all reads of w done
            if (h < NHOPS - 1) {                   // zero own w chunk for next hop
                for (int i = tid; i < NB * VC_U; i += NTHR) {
                    const int b = i >> 6, v = i & 63;
                    w[(size_t)b * NV + vbase + v] = 0.f;
                }
            }
        }
        grid.sync();

        // ---- P4a: partial-of-partials (512 blocks, each 1/8 of 500 parts) ---
        {
            const int q = bid >> 6;                 // 0..7
            const int e = ((bid & 63) << 8) + tid;  // element 0..16383
            const int p0 = (q * NPART_U) >> 3, p1 = ((q + 1) * NPART_U) >> 3;
            float s = 0.f;
#pragma unroll 7
            for (int p = p0; p < p1; ++p)
                s += part[(size_t)p * (NB * NH) + e];
            part2[q * (NB * NH) + e] = s;
        }
        grid.sync();

        // ---- P4b: final 8-way sum + u_in -> u_next (+ bf16 split) -----------
        if (gtid < NB * NH) {
            float s = ucur[gtid];
#pragma unroll
            for (int q = 0; q < NQ; ++q)
                s += part2[q * (NB * NH) + gtid];
            unext[gtid] = s;
            if (h < NHOPS - 1) {
                const unsigned short hh = f2bf(s);
                uh[gtid] = hh;
                ul[gtid] = f2bf(s - bf2f(hh));
            }
        }
        grid.sync();
    }
}

// ---------------------------------------------------------------------------
// Fallback (known-good gather path, also used if coop launch fails).
// ---------------------------------------------------------------------------
__global__ __launch_bounds__(128)
void scores_gather_kernel(const int* __restrict__ inputs,
                          const float* __restrict__ Ctab,
                          const float* __restrict__ u_in,
                          const int* __restrict__ lengths,
                          float* __restrict__ scores) {
    const int bm = blockIdx.x;
    const int b = bm / NM;
    const int tid = threadIdx.x;
    __shared__ int idx[NL];
    if (tid < NL) idx[tid] = inputs[bm * NL + tid];
    __syncthreads();
    const int hoff = tid * 4;
    const float4 u4 = *reinterpret_cast<const float4*>(u_in + b * NH + hoff);
    float p = 0.f;
    for (int l = 0; l < NL; ++l) {
        const float4 v = *reinterpret_cast<const float4*>(
            Ctab + (size_t)idx[l] * NH + hoff);
        p += u4.x * v.x + u4.y * v.y + u4.z * v.z + u4.w * v.w;
    }
#pragma unroll
    for (int off = 32; off; off >>= 1) p += __shfl_down(p, off, 64);
    __shared__ float w2[2];
    if ((tid & 63) == 0) w2[tid >> 6] = p;
    __syncthreads();
    if (tid == 0) {
        float sres = w2[0] + w2[1];
        if (lengths[bm] == 0) sres = NEG_INF;
        scores[bm] = sres;
    }
}

__global__ __launch_bounds__(128)
void softmax_kernel(const float* __restrict__ scores,
                    float* __restrict__ attn_ws,
                    float* __restrict__ attn_out) {
    const int b = blockIdx.x;
    const int tid = threadIdx.x;
    const float s = scores[b * NM + tid];
    float p = s;
#pragma unroll
    for (int off = 32; off; off >>= 1) p = fmaxf(p, __shfl_down(p, off, 64));
    __shared__ float w2[2];
    if ((tid & 63) == 0) w2[tid >> 6] = p;
    __syncthreads();
    const float mx = fmaxf(w2[0], w2[1]);
    const float e = expf(s - mx);
    float q = e;
#pragma unroll
    for (int off = 32; off; off >>= 1) q += __shfl_down(q, off, 64);
    __shared__ float w3[2];
    if ((tid & 63) == 0) w3[tid >> 6] = q;
    __syncthreads();
    const float a = e / (w3[0] + w3[1]);
    attn_ws[b * NM + tid] = a;
    attn_out[b * NM + tid] = a;
}

__global__ __launch_bounds__(512)
void update_gather_kernel(const int* __restrict__ inputs,
                          const float* __restrict__ Ctab,
                          const float* __restrict__ u_in,
                          const float* __restrict__ attn,
                          float* __restrict__ u_out) {
    const int b = blockIdx.x;
    const int tid = threadIdx.x;
    __shared__ float a_s[NM];
    __shared__ int idx_s[NM * NL];
    if (tid < NM) a_s[tid] = attn[b * NM + tid];
    for (int i = tid; i < NM * NL; i += 512) idx_s[i] = inputs[b * NM * NL + i];
    __syncthreads();
    float acc = u_in[b * NH + tid];
    for (int m = 0; m < NM; ++m) {
        const float a = a_s[m];
        float part = 0.f;
        for (int l = 0; l < NL; ++l) {
            part += Ctab[(size_t)idx_s[m * NL + l] * NH + tid];
        }
        acc += a * part;
    }
    u_out[b * NH + tid] = acc;
}

static void launch_fallback(const int* inputs, const int* lengths,
                            const float* enc, const float* C,
                            float* out, float* ws, hipStream_t stream) {
    const size_t TAB = (size_t)NV * NH;
    const size_t UE  = (size_t)NB * NH;
    float* scores  = ws;
    float* attn_ws = ws + NB * NM;
    float* u1      = attn_ws + NB * NM;
    float* u2      = u1 + UE;
    float* attns   = out + NB * NH;
    const float* uin = enc;
    float* uou[NHOPS] = {u1, u2, out};
    for (int h = 0; h < NHOPS; ++h) {
        scores_gather_kernel<<<NB * NM, 128, 0, stream>>>(
            inputs, C + (size_t)h * TAB, uin, lengths, scores);
        softmax_kernel<<<NB, 128, 0, stream>>>(
            scores, attn_ws, attns + (size_t)h * NB * NM);
        update_gather_kernel<<<NB, 512, 0, stream>>>(
            inputs, C + (size_t)(h + 1) * TAB, uin, attn_ws, uou[h]);
        uin = uou[h];
    }
}

// ---------------------------------------------------------------------------
extern "C" void kernel_launch(void* const* d_in, const int* in_sizes, int n_in,
                              void* d_out, int out_size, void* d_ws, size_t ws_size,
                              hipStream_t stream) {
    const int*   inputs  = (const int*)d_in[0];
    const int*   lengths = (const int*)d_in[1];
    const float* enc     = (const float*)d_in[2];
    const float* C       = (const float*)d_in[3];

    float* out = (float*)d_out;
    float* ws  = (float*)d_ws;

    const size_t BV = (size_t)NB * NV;      // 1,024,000
    const size_t UE = (size_t)NB * NH;      // 16,384

    const size_t need_f = 2 * BV + (size_t)NPART_U * UE + (size_t)NQ * UE
                        + 2 * UE + UE;      // D,w,part,part2,u1,u2,uh/ul
    if (ws_size >= need_f * sizeof(float)) {
        float* D     = ws;
        float* w     = D + BV;
        float* part  = w + BV;
        float* part2 = part + (size_t)NPART_U * UE;
        float* u1    = part2 + (size_t)NQ * UE;
        float* u2    = u1 + UE;
        unsigned short* uh = (unsigned short*)(u2 + UE);
        unsigned short* ul = uh + UE;

        void* args[] = {(void*)&inputs, (void*)&lengths, (void*)&enc, (void*)&C,
                        (void*)&out, (void*)&D, (void*)&w, (void*)&part,
                        (void*)&part2, (void*)&u1, (void*)&u2,
                        (void*)&uh, (void*)&ul};
        hipError_t err = hipLaunchCooperativeKernel(
            (const void*)memnn_fused, dim3(NBLK), dim3(NTHR), args, 0, stream);
        if (err != hipSuccess) {
            launch_fallback(inputs, lengths, enc, C, out, ws, stream);
        }
    } else {
        launch_fallback(inputs, lengths, enc, C, out, ws, stream);
    }
}

// Round 7
// 312.876 us; speedup vs baseline: 4.2651x; 4.2651x over previous
//
#include <hip/hip_runtime.h>

#define NB 32
#define NM 128
#define NL 32
#define NH 512
#define NV 32000
#define NHOPS 3
#define NEG_INF -1e9f

#define VC_U 128
#define NPART (NV / VC_U)       // 250 split-K partials

typedef __attribute__((ext_vector_type(8))) short bf16x8;
typedef __attribute__((ext_vector_type(4))) float f32x4;

__device__ __forceinline__ unsigned short f2bf(float x) {
    unsigned u = __float_as_uint(x);
    return (unsigned short)((u + 0x7fffu + ((u >> 16) & 1u)) >> 16);
}
__device__ __forceinline__ float bf2f(unsigned short h) {
    return __uint_as_float(((unsigned)h) << 16);
}

// ---------------------------------------------------------------------------
// init: zero w; split enc -> uh/ul. grid 256 x 256.
// ---------------------------------------------------------------------------
__global__ __launch_bounds__(256)
void init_kernel(const float* __restrict__ enc, float* __restrict__ w,
                 unsigned short* __restrict__ uh, unsigned short* __restrict__ ul) {
    const int gtid = blockIdx.x * 256 + threadIdx.x;     // 65536 threads
    float4* w4 = reinterpret_cast<float4*>(w);
    for (int i = gtid; i < (NB * NV) / 4; i += 256 * 256)
        w4[i] = make_float4(0.f, 0.f, 0.f, 0.f);
    if (gtid < NB * NH) {
        const float x = enc[gtid];
        const unsigned short h = f2bf(x);
        uh[gtid] = h;
        ul[gtid] = f2bf(x - bf2f(h));
    }
}

// ---------------------------------------------------------------------------
// gemm_D: D[b][v] = u[b].C[v]  (M=32, N=32000, K=512), split-bf16, NO LDS.
// B-fragment (8 consecutive h of one C row) is contiguous in memory: build it
// from two coalesced float4 loads + in-register hi/lo split. 500 x 256 (4
// waves), wave owns one v-tile16 and both b-tiles. ~8 waves/SIMD occupancy.
// ---------------------------------------------------------------------------
__global__ __launch_bounds__(256)
void gemm_D_kernel(const unsigned short* __restrict__ uh,
                   const unsigned short* __restrict__ ul,
                   const float* __restrict__ Ct,
                   float* __restrict__ D) {
    const int tid = threadIdx.x;
    const int wv = tid >> 6, lane = tid & 63;
    const int n = lane & 15;                 // v within tile / b within m-tile
    const int kblk = (lane >> 4) << 3;       // 0,8,16,24
    const int vrow = (blockIdx.x * 4 + wv) * 16 + n;

    const float* Crow = Ct + ((size_t)vrow << 9) + kblk;
    const unsigned short* ua0 = uh + (n << 9) + kblk;
    const unsigned short* la0 = ul + (n << 9) + kblk;
    const unsigned short* ua1 = uh + ((n + 16) << 9) + kblk;
    const unsigned short* la1 = ul + ((n + 16) << 9) + kblk;

    f32x4 acc0 = {0.f, 0.f, 0.f, 0.f};
    f32x4 acc1 = {0.f, 0.f, 0.f, 0.f};

#pragma unroll 4
    for (int kt = 0; kt < 16; ++kt) {
        const int ko = kt * 32;
        const float4 x0 = *reinterpret_cast<const float4*>(Crow + ko);
        const float4 x1 = *reinterpret_cast<const float4*>(Crow + ko + 4);
        float v[8] = {x0.x, x0.y, x0.z, x0.w, x1.x, x1.y, x1.z, x1.w};
        union { bf16x8 v8; unsigned u4[4]; } H, L;
#pragma unroll
        for (int i = 0; i < 4; ++i) {
            const unsigned short h0 = f2bf(v[2 * i]), h1 = f2bf(v[2 * i + 1]);
            const unsigned short l0 = f2bf(v[2 * i] - bf2f(h0));
            const unsigned short l1 = f2bf(v[2 * i + 1] - bf2f(h1));
            H.u4[i] = (unsigned)h0 | ((unsigned)h1 << 16);
            L.u4[i] = (unsigned)l0 | ((unsigned)l1 << 16);
        }
        const bf16x8 bh = H.v8, bl = L.v8;
        const bf16x8 ah0 = *reinterpret_cast<const bf16x8*>(ua0 + ko);
        const bf16x8 al0 = *reinterpret_cast<const bf16x8*>(la0 + ko);
        const bf16x8 ah1 = *reinterpret_cast<const bf16x8*>(ua1 + ko);
        const bf16x8 al1 = *reinterpret_cast<const bf16x8*>(la1 + ko);
        acc0 = __builtin_amdgcn_mfma_f32_16x16x32_bf16(ah0, bh, acc0, 0, 0, 0);
        acc0 = __builtin_amdgcn_mfma_f32_16x16x32_bf16(ah0, bl, acc0, 0, 0, 0);
        acc0 = __builtin_amdgcn_mfma_f32_16x16x32_bf16(al0, bh, acc0, 0, 0, 0);
        acc1 = __builtin_amdgcn_mfma_f32_16x16x32_bf16(ah1, bh, acc1, 0, 0, 0);
        acc1 = __builtin_amdgcn_mfma_f32_16x16x32_bf16(ah1, bl, acc1, 0, 0, 0);
        acc1 = __builtin_amdgcn_mfma_f32_16x16x32_bf16(al1, bh, acc1, 0, 0, 0);
    }
    // C/D layout: col = lane&15 (v), row = (lane>>4)*4 + r (b)
    const int r0 = (lane >> 4) << 2;
#pragma unroll
    for (int r = 0; r < 4; ++r) {
        D[(size_t)(r0 + r) * NV + vrow]      = acc0[r];
        D[(size_t)(16 + r0 + r) * NV + vrow] = acc1[r];
    }
}

// ---------------------------------------------------------------------------
// scores + softmax + w-scatter: one block per b (256 thr; tid<128 = m).
// ---------------------------------------------------------------------------
__global__ __launch_bounds__(256)
void scores_kernel(const float* __restrict__ D,
                   const int* __restrict__ inputs,
                   const int* __restrict__ lengths,
                   float* __restrict__ attn_out,   // [32][128]
                   float* __restrict__ w) {        // [32][NV], pre-zeroed
    const int b = blockIdx.x, tid = threadIdx.x;
    int idx[NL];
    float s = NEG_INF;
    if (tid < NM) {
        const int4* ip = reinterpret_cast<const int4*>(
            inputs + (((b << 7) + tid) << 5));
        const float* Db = D + (size_t)b * NV;
        float acc = 0.f;
#pragma unroll
        for (int q = 0; q < 8; ++q) {
            const int4 i4 = ip[q];
            idx[q * 4 + 0] = i4.x; idx[q * 4 + 1] = i4.y;
            idx[q * 4 + 2] = i4.z; idx[q * 4 + 3] = i4.w;
        }
#pragma unroll
        for (int l = 0; l < NL; ++l) acc += Db[idx[l]];
        s = (lengths[(b << 7) + tid] == 0) ? NEG_INF : acc;
    }
    __shared__ float red[2];
    float mx = s;
#pragma unroll
    for (int o = 32; o; o >>= 1) mx = fmaxf(mx, __shfl_xor(mx, o, 64));
    if (tid < NM && (tid & 63) == 0) red[tid >> 6] = mx;
    __syncthreads();
    mx = fmaxf(red[0], red[1]);
    const float ee = (tid < NM) ? expf(s - mx) : 0.f;
    float sum = ee;
#pragma unroll
    for (int o = 32; o; o >>= 1) sum += __shfl_xor(sum, o, 64);
    __syncthreads();
    if (tid < NM && (tid & 63) == 0) red[tid >> 6] = sum;
    __syncthreads();
    if (tid < NM) {
        const float a = ee / (red[0] + red[1]);
        attn_out[(b << 7) + tid] = a;
        float* wb = w + (size_t)b * NV;
#pragma unroll
        for (int l = 0; l < NL; ++l) atomicAdd(&wb[idx[l]], a);
    }
}

// ---------------------------------------------------------------------------
// gemm_U (split-K): part[blk][b][h] = sum_{v in 128-chunk} w[b][v]*C[v][h]
// 250 blocks x 512 thr (thread owns one h). w read as wave-uniform global
// float4 (L1 broadcast) -- no DS-pipe bottleneck. Zeroes its own w chunk
// after reading (for the next hop's scatter).
// ---------------------------------------------------------------------------
__global__ __launch_bounds__(512)
void gemm_U_kernel(float* __restrict__ w,
                   const float* __restrict__ Cn,
                   float* __restrict__ part,       // [NPART][32][512]
                   int zero_w) {
    const int tid = threadIdx.x;
    const int vbase = blockIdx.x * VC_U;
    float acc[NB];
#pragma unroll
    for (int b = 0; b < NB; ++b) acc[b] = 0.f;

    const float* Cp = Cn + ((size_t)vbase << 9) + tid;
    for (int v = 0; v < VC_U; v += 4) {
        const float c0 = Cp[(size_t)(v + 0) << 9];
        const float c1 = Cp[(size_t)(v + 1) << 9];
        const float c2 = Cp[(size_t)(v + 2) << 9];
        const float c3 = Cp[(size_t)(v + 3) << 9];
#pragma unroll
        for (int b = 0; b < NB; ++b) {
            const float4 wv4 = *reinterpret_cast<const float4*>(
                w + (size_t)b * NV + vbase + v);          // wave-uniform
            acc[b] += wv4.x * c0 + wv4.y * c1 + wv4.z * c2 + wv4.w * c3;
        }
    }
    float* pb = part + (size_t)blockIdx.x * (NB * NH);
#pragma unroll
    for (int b = 0; b < NB; ++b) pb[(b << 9) + tid] = acc[b];

    if (zero_w) {
        __syncthreads();                     // all w reads in this block done
        for (int i = tid; i < NB * VC_U; i += 512) {
            const int b = i >> 7, v = i & 127;
            w[(size_t)b * NV + vbase + v] = 0.f;
        }
    }
}

// ---------------------------------------------------------------------------
// reduce partials (4-way q-split) + u_in -> u_next; fused bf16 hi/lo split.
// grid 256 x 256; block covers 64 elements.
// ---------------------------------------------------------------------------
__global__ __launch_bounds__(256)
void reduce_u_kernel(const float* __restrict__ u_in,
                     const float* __restrict__ part,
                     float* __restrict__ u_out,
                     unsigned short* __restrict__ uh,
                     unsigned short* __restrict__ ul) {
    const int j = threadIdx.x & 63, q = threadIdx.x >> 6;
    const int e = blockIdx.x * 64 + j;
    const int p0 = (q * NPART) >> 2, p1 = ((q + 1) * NPART) >> 2;
    float s = 0.f;
#pragma unroll 4
    for (int p = p0; p < p1; ++p) s += part[(size_t)p * (NB * NH) + e];
    __shared__ float red[4][64];
    red[q][j] = s;
    __syncthreads();
    if (threadIdx.x < 64) {
        const float t = u_in[e] + red[0][j] + red[1][j] + red[2][j] + red[3][j];
        u_out[e] = t;
        const unsigned short h = f2bf(t);
        uh[e] = h;
        ul[e] = f2bf(t - bf2f(h));
    }
}

// ---------------------------------------------------------------------------
// Tiny-workspace fallback (known-good gather path).
// ---------------------------------------------------------------------------
__global__ __launch_bounds__(128)
void scores_gather_kernel(const int* __restrict__ inputs,
                          const float* __restrict__ Ctab,
                          const float* __restrict__ u_in,
                          const int* __restrict__ lengths,
                          float* __restrict__ scores) {
    const int bm = blockIdx.x;
    const int b = bm / NM;
    const int tid = threadIdx.x;
    __shared__ int idx[NL];
    if (tid < NL) idx[tid] = inputs[bm * NL + tid];
    __syncthreads();
    const int hoff = tid * 4;
    const float4 u4 = *reinterpret_cast<const float4*>(u_in + b * NH + hoff);
    float p = 0.f;
    for (int l = 0; l < NL; ++l) {
        const float4 v = *reinterpret_cast<const float4*>(
            Ctab + (size_t)idx[l] * NH + hoff);
        p += u4.x * v.x + u4.y * v.y + u4.z * v.z + u4.w * v.w;
    }
#pragma unroll
    for (int off = 32; off; off >>= 1) p += __shfl_down(p, off, 64);
    __shared__ float w2[2];
    if ((tid & 63) == 0) w2[tid >> 6] = p;
    __syncthreads();
    if (tid == 0) {
        float sres = w2[0] + w2[1];
        if (lengths[bm] == 0) sres = NEG_INF;
        scores[bm] = sres;
    }
}

__global__ __launch_bounds__(128)
void softmax_kernel(const float* __restrict__ scores,
                    float* __restrict__ attn_ws,
                    float* __restrict__ attn_out) {
    const int b = blockIdx.x;
    const int tid = threadIdx.x;
    const float s = scores[b * NM + tid];
    float p = s;
#pragma unroll
    for (int off = 32; off; off >>= 1) p = fmaxf(p, __shfl_down(p, off, 64));
    __shared__ float w2[2];
    if ((tid & 63) == 0) w2[tid >> 6] = p;
    __syncthreads();
    const float mx = fmaxf(w2[0], w2[1]);
    const float e = expf(s - mx);
    float q = e;
#pragma unroll
    for (int off = 32; off; off >>= 1) q += __shfl_down(q, off, 64);
    __shared__ float w3[2];
    if ((tid & 63) == 0) w3[tid >> 6] = q;
    __syncthreads();
    const float a = e / (w3[0] + w3[1]);
    attn_ws[b * NM + tid] = a;
    attn_out[b * NM + tid] = a;
}

__global__ __launch_bounds__(512)
void update_gather_kernel(const int* __restrict__ inputs,
                          const float* __restrict__ Ctab,
                          const float* __restrict__ u_in,
                          const float* __restrict__ attn,
                          float* __restrict__ u_out) {
    const int b = blockIdx.x;
    const int tid = threadIdx.x;
    __shared__ float a_s[NM];
    __shared__ int idx_s[NM * NL];
    if (tid < NM) a_s[tid] = attn[b * NM + tid];
    for (int i = tid; i < NM * NL; i += 512) idx_s[i] = inputs[b * NM * NL + i];
    __syncthreads();
    float acc = u_in[b * NH + tid];
    for (int m = 0; m < NM; ++m) {
        const float a = a_s[m];
        float part = 0.f;
        for (int l = 0; l < NL; ++l) {
            part += Ctab[(size_t)idx_s[m * NL + l] * NH + tid];
        }
        acc += a * part;
    }
    u_out[b * NH + tid] = acc;
}

static void launch_fallback(const int* inputs, const int* lengths,
                            const float* enc, const float* C,
                            float* out, float* ws, hipStream_t stream) {
    const size_t TAB = (size_t)NV * NH;
    const size_t UE  = (size_t)NB * NH;
    float* scores  = ws;
    float* attn_ws = ws + NB * NM;
    float* u1      = attn_ws + NB * NM;
    float* u2      = u1 + UE;
    float* attns   = out + NB * NH;
    const float* uin = enc;
    float* uou[NHOPS] = {u1, u2, out};
    for (int h = 0; h < NHOPS; ++h) {
        scores_gather_kernel<<<NB * NM, 128, 0, stream>>>(
            inputs, C + (size_t)h * TAB, uin, lengths, scores);
        softmax_kernel<<<NB, 128, 0, stream>>>(
            scores, attn_ws, attns + (size_t)h * NB * NM);
        update_gather_kernel<<<NB, 512, 0, stream>>>(
            inputs, C + (size_t)(h + 1) * TAB, uin, attn_ws, uou[h]);
        uin = uou[h];
    }
}

// ---------------------------------------------------------------------------
extern "C" void kernel_launch(void* const* d_in, const int* in_sizes, int n_in,
                              void* d_out, int out_size, void* d_ws, size_t ws_size,
                              hipStream_t stream) {
    const int*   inputs  = (const int*)d_in[0];
    const int*   lengths = (const int*)d_in[1];
    const float* enc     = (const float*)d_in[2];
    const float* C       = (const float*)d_in[3];

    float* out   = (float*)d_out;
    float* attns = out + NB * NH;

    const size_t TAB = (size_t)NV * NH;
    const size_t BV  = (size_t)NB * NV;     // 1,024,000
    const size_t UE  = (size_t)NB * NH;     // 16,384
    float* ws = (float*)d_ws;

    const size_t need_f = 2 * BV + (size_t)NPART * UE + 2 * UE + UE;
    if (ws_size >= need_f * sizeof(float)) {
        float* D    = ws;
        float* w    = D + BV;
        float* part = w + BV;
        float* u1   = part + (size_t)NPART * UE;
        float* u2   = u1 + UE;
        unsigned short* uh = (unsigned short*)(u2 + UE);
        unsigned short* ul = uh + UE;

        init_kernel<<<256, 256, 0, stream>>>(enc, w, uh, ul);
        const float* uin[NHOPS]   = {enc, u1, u2};
        float*       unext[NHOPS] = {u1, u2, out};
        for (int h = 0; h < NHOPS; ++h) {
            gemm_D_kernel<<<NV / 64, 256, 0, stream>>>(
                uh, ul, C + (size_t)h * TAB, D);
            scores_kernel<<<NB, 256, 0, stream>>>(
                D, inputs, lengths, attns + (size_t)h * NB * NM, w);
            gemm_U_kernel<<<NPART, 512, 0, stream>>>(
                w, C + (size_t)(h + 1) * TAB, part, h < NHOPS - 1 ? 1 : 0);
            reduce_u_kernel<<<256, 256, 0, stream>>>(
                uin[h], part, unext[h], uh, ul);
        }
    } else {
        launch_fallback(inputs, lengths, enc, C, out, ws, stream);
    }
}